// Round 5
// baseline (4253.115 us; speedup 1.0000x reference)
//
#include <hip/hip_runtime.h>
#include <cstdint>
#include <cstddef>

// LayerNormLSTM on MI355X.
// Phase 0: fp32->bf16 conversion of x, Wi, Wh; tagged init of h(0).
// Phase 1: Gpre = x @ Wi^T (bf16 MFMA), t-major output [t][b][2048].
// Phase 1.5: in-place row LN (scale=b1, shift=s1).
// Phase 2: persistent recurrence, 64 wgs = 4 teams(16 samples) x 16 slices.
//   R5: TWO exchanges per step (was 3):
//    - hop G: producers post raw MFMA gates as tagged u64 (tag=t+1 | 2 bf16)
//      straight from acc regs; sample OWNER wg polls its contiguous 8KB slot.
//    - hop H: owner computes LN-A, acts, c, LN-C, h locally (intra-wg
//      reductions) and posts h as tagged u64 (tag=t | 2 bf16).
//   No fences, no acks, no counters, no memsets; poll loops s_sleep-throttled.

typedef float  f32x4 __attribute__((ext_vector_type(4)));
typedef __bf16 bf16x8 __attribute__((ext_vector_type(8)));
typedef unsigned int u32x4 __attribute__((ext_vector_type(4)));
typedef unsigned short u16x4 __attribute__((ext_vector_type(4)));

#define DEV __device__ __forceinline__

DEV unsigned short f2b(float f){
  unsigned int u = __builtin_bit_cast(unsigned int, f);
  unsigned int r = (u + 0x7FFFu + ((u >> 16) & 1u)) >> 16;
  return (unsigned short)r;
}
DEV float b2f(unsigned short s){
  unsigned int u = ((unsigned int)s) << 16;
  return __builtin_bit_cast(float, u);
}

// ---------------- Phase 0: conversion ----------------
__global__ __launch_bounds__(256) void conv_bf16(const float* __restrict__ src,
                                                 unsigned short* __restrict__ dst,
                                                 int n4){
  int i = blockIdx.x * 256 + threadIdx.x;
  if (i >= n4) return;
  f32x4 v = ((const f32x4*)src)[i];
  u16x4 o;
  #pragma unroll
  for (int j = 0; j < 4; ++j) o[j] = f2b(v[j]);
  ((u16x4*)dst)[i] = o;
}

// h(0): tagged u64 (tag=0 | cols 2p,2p+1)
__global__ __launch_bounds__(256) void init_h(const float* __restrict__ hx,
                                              unsigned long long* __restrict__ hbuf){
  int s = blockIdx.x;        // 0..63
  int p = threadIdx.x;       // 0..255
  float h0 = hx[s * 512 + 2 * p];
  float h1 = hx[s * 512 + 2 * p + 1];
  unsigned long long v = (unsigned long long)f2b(h0) |
                         ((unsigned long long)f2b(h1) << 16);
  hbuf[(size_t)s * 256 + p] = v;
}

// ---------------- Phase 1: Gpre = Xb @ Wib^T (t-major output) ----------------
__global__ __launch_bounds__(256, 2) void gemm_gi(const unsigned short* __restrict__ Xb,
                                                  const unsigned short* __restrict__ Wib,
                                                  unsigned short* __restrict__ Gp){
  __shared__ unsigned short As[128 * 48];
  __shared__ unsigned short Bs[128 * 48];
  const int tid = threadIdx.x;
  const int m0 = blockIdx.x * 128;
  const int n0 = blockIdx.y * 128;
  const int w = tid >> 6, lane = tid & 63;
  const int lr = lane & 15, lq = lane >> 4;
  const int wm = (w & 1) * 64, wn = (w >> 1) * 64;
  const int sr = tid >> 2;
  const int sc = (tid & 3) * 8;
  const unsigned short* gx = Xb + (size_t)(m0 + sr) * 512 + sc;
  const unsigned short* gw = Wib + (size_t)(n0 + sr) * 512 + sc;
  f32x4 acc[4][4] = {};
  for (int kb = 0; kb < 16; ++kb){
    u32x4 a0 = *(const u32x4*)(gx + kb * 32);
    u32x4 a1 = *(const u32x4*)(gx + 64 * 512 + kb * 32);
    u32x4 b0 = *(const u32x4*)(gw + kb * 32);
    u32x4 b1 = *(const u32x4*)(gw + 64 * 512 + kb * 32);
    __syncthreads();
    *(u32x4*)&As[sr * 48 + sc] = a0;
    *(u32x4*)&As[(sr + 64) * 48 + sc] = a1;
    *(u32x4*)&Bs[sr * 48 + sc] = b0;
    *(u32x4*)&Bs[(sr + 64) * 48 + sc] = b1;
    __syncthreads();
    bf16x8 af[4], bfv[4];
    #pragma unroll
    for (int mi = 0; mi < 4; ++mi) af[mi] = *(const bf16x8*)&As[(wm + mi * 16 + lr) * 48 + lq * 8];
    #pragma unroll
    for (int ni = 0; ni < 4; ++ni) bfv[ni] = *(const bf16x8*)&Bs[(wn + ni * 16 + lr) * 48 + lq * 8];
    #pragma unroll
    for (int mi = 0; mi < 4; ++mi)
      #pragma unroll
      for (int ni = 0; ni < 4; ++ni)
        acc[mi][ni] = __builtin_amdgcn_mfma_f32_16x16x32_bf16(af[mi], bfv[ni], acc[mi][ni], 0, 0, 0);
  }
  // t-major scatter: row_old = b*512+t -> row_new = t*64 + b
  #pragma unroll
  for (int mi = 0; mi < 4; ++mi){
    const int rowb = m0 + wm + mi * 16 + lq * 4;
    #pragma unroll
    for (int ni = 0; ni < 4; ++ni){
      const int col = n0 + wn + ni * 16 + lr;
      #pragma unroll
      for (int r = 0; r < 4; ++r){
        const int ro = rowb + r;
        const int rn = ((ro & 511) << 6) | (ro >> 9);
        Gp[(size_t)rn * 2048 + col] = f2b(acc[mi][ni][r]);
      }
    }
  }
}

// ---------------- Phase 1.5: row LN (scale=b1, shift=s1) ----------------
__global__ __launch_bounds__(256) void ln_rows(unsigned short* __restrict__ G,
                                               const float* __restrict__ b1,
                                               const float* __restrict__ s1){
  const int row = blockIdx.x;
  const int tid = threadIdx.x;
  unsigned short* rp = G + (size_t)row * 2048 + tid * 8;
  u32x4 raw = *(const u32x4*)rp;
  float x[8];
  #pragma unroll
  for (int j = 0; j < 8; ++j){
    unsigned int word = raw[j >> 1];
    unsigned short us = (j & 1) ? (unsigned short)(word >> 16) : (unsigned short)(word & 0xFFFF);
    x[j] = b2f(us);
  }
  float s = 0.f, q = 0.f;
  #pragma unroll
  for (int j = 0; j < 8; ++j){ s += x[j]; q += x[j] * x[j]; }
  #pragma unroll
  for (int o = 1; o < 64; o <<= 1){ s += __shfl_xor(s, o); q += __shfl_xor(q, o); }
  __shared__ float ps[4][2];
  const int wv = tid >> 6;
  if ((tid & 63) == 0){ ps[wv][0] = s; ps[wv][1] = q; }
  __syncthreads();
  s = ps[0][0] + ps[1][0] + ps[2][0] + ps[3][0];
  q = ps[0][1] + ps[1][1] + ps[2][1] + ps[3][1];
  const float mu = s * (1.f / 2048.f);
  const float inv = rsqrtf((q - s * mu) + 1e-5f);
  const float* b1p = b1 + tid * 8;
  const float* s1p = s1 + tid * 8;
  u32x4 outw;
  #pragma unroll
  for (int j = 0; j < 4; ++j){
    float y0 = b1p[2 * j]     * ((x[2 * j]     - mu) * inv) + s1p[2 * j];
    float y1 = b1p[2 * j + 1] * ((x[2 * j + 1] - mu) * inv) + s1p[2 * j + 1];
    outw[j] = (unsigned int)f2b(y0) | ((unsigned int)f2b(y1) << 16);
  }
  *(u32x4*)rp = outw;
}

// ---------------- Phase 2: persistent recurrence ----------------
__global__ __launch_bounds__(512, 2) void lstm_rec(
    const unsigned short* __restrict__ Gi,   // [512 t][64 b][2048] bf16 post-LN
    const unsigned short* __restrict__ Whb,  // [2048][512] bf16
    const float* __restrict__ bias,
    const float* __restrict__ b2, const float* __restrict__ s2,
    const float* __restrict__ b3, const float* __restrict__ s3,
    const float* __restrict__ cx,
    unsigned long long* __restrict__ hbuf,   // [64][256] tagged u64 (tag=t)
    unsigned long long* __restrict__ gbuf,   // [64][1024] tagged u64 (tag=t+1)
    float* __restrict__ out){
  const int tid = threadIdx.x;
  const int tm = (blockIdx.x >> 1) & 3;                        // team
  const int ks = ((blockIdx.x >> 3) << 1) | (blockIdx.x & 1);  // slice
  const int w = tid >> 6;
  const int lane = tid & 63;
  const int lr = lane & 15, lq = lane >> 4;

  // producer role: wave w owns gate rows type*512 + ks*32 + jloc
  const int type = w >> 1;
  const int jloc = (w & 1) * 16 + lr;
  const int row_g = type * 512 + ks * 32 + jloc;

  // Wh B-fragments in registers (B layout: n=lane&15, k=(lane>>4)*8+j)
  bf16x8 bfr[16];
  {
    const unsigned short* wr = Whb + (size_t)row_g * 512 + lq * 8;
    #pragma unroll
    for (int kk = 0; kk < 16; ++kk) bfr[kk] = *(const bf16x8*)(wr + kk * 32);
  }

  // owner role: this wg owns sample s_own; thread tid <-> col tid / gates 4tid..4tid+3
  const int s_own = tm * 16 + ks;
  float c_val = cx[(size_t)s_own * 512 + tid];
  const float b3j = b3[tid], s3j = s3[tid];

  __shared__ unsigned short hlds[16 * 520];   // team h staging (2-way alias ok)
  __shared__ float actL[2048];
  __shared__ float p2L[2048];                 // b2
  __shared__ float psbL[2048];                // s2 + bias
  __shared__ float red[8][2];

  // one-time param preload
  {
    f32x4 vb2 = *(const f32x4*)(b2 + 4 * tid);
    f32x4 vs2 = *(const f32x4*)(s2 + 4 * tid);
    f32x4 vbi = *(const f32x4*)(bias + 4 * tid);
    f32x4 vsb;
    #pragma unroll
    for (int j = 0; j < 4; ++j) vsb[j] = vs2[j] + vbi[j];
    *(f32x4*)&p2L[4 * tid] = vb2;
    *(f32x4*)&psbL[4 * tid] = vsb;
  }
  __syncthreads();

  const unsigned long long* hteam = hbuf + (size_t)tm * 4096;
  unsigned long long* gb_own = gbuf + (size_t)s_own * 1024;

  for (int t = 0; t < 512; ++t){
    // ---- hop H consume: poll team h(t), tagged; decode into LDS ----
    unsigned long long hv[8];
    {
      const unsigned tg = (unsigned)t;
      for (;;){
        bool ok = true;
        #pragma unroll
        for (int j = 0; j < 8; ++j)
          hv[j] = __hip_atomic_load(hteam + tid * 8 + j, __ATOMIC_RELAXED, __HIP_MEMORY_SCOPE_AGENT);
        #pragma unroll
        for (int j = 0; j < 8; ++j) ok &= ((unsigned)(hv[j] >> 32) == tg);
        if (__all((int)ok)) break;
        __builtin_amdgcn_s_sleep(1);
      }
    }
    #pragma unroll
    for (int j = 0; j < 8; ++j){
      const int g = tid * 8 + j;               // team u64 idx: smp=g>>8, pair=g&255
      *(unsigned int*)&hlds[(g >> 8) * 520 + (g & 255) * 2] = (unsigned)hv[j];
    }
    __syncthreads();                                   // B0

    // ---- MFMA: [16 smp x 512] @ [512 x 16 rows] ----
    f32x4 acc = {0.f, 0.f, 0.f, 0.f};
    #pragma unroll
    for (int kk = 0; kk < 16; ++kk){
      bf16x8 af = *(const bf16x8*)&hlds[lr * 520 + lq * 8 + kk * 32];
      acc = __builtin_amdgcn_mfma_f32_16x16x32_bf16(af, bfr[kk], acc, 0, 0, 0);
    }

    // ---- hop G produce: post tagged gate pairs straight from acc ----
    {
      const unsigned long long tg = (unsigned long long)(unsigned)(t + 1) << 32;
      float gn[4];
      #pragma unroll
      for (int r = 0; r < 4; ++r) gn[r] = __shfl_xor(acc[r], 1);
      if ((lr & 1) == 0){
        const int gidx = row_g >> 1;
        #pragma unroll
        for (int r = 0; r < 4; ++r){
          const int sm = tm * 16 + lq * 4 + r;   // D row = sample
          unsigned long long v = tg | (unsigned long long)f2b(acc[r]) |
                                 ((unsigned long long)f2b(gn[r]) << 16);
          __hip_atomic_store(gbuf + (size_t)sm * 1024 + gidx, v,
                             __ATOMIC_RELAXED, __HIP_MEMORY_SCOPE_AGENT);
        }
      }
    }

    // gi prefetch for own sample (independent of gate arrival)
    const unsigned long long giw =
        *(const unsigned long long*)(Gi + ((size_t)t * 64 + s_own) * 2048 + 4 * tid);

    // ---- hop G consume: poll own sample's 2048 gates (contiguous 8KB) ----
    unsigned long long g0, g1;
    {
      const unsigned tg = (unsigned)(t + 1);
      for (;;){
        g0 = __hip_atomic_load(gb_own + 2 * tid,     __ATOMIC_RELAXED, __HIP_MEMORY_SCOPE_AGENT);
        g1 = __hip_atomic_load(gb_own + 2 * tid + 1, __ATOMIC_RELAXED, __HIP_MEMORY_SCOPE_AGENT);
        bool ok = ((unsigned)(g0 >> 32) == tg) & ((unsigned)(g1 >> 32) == tg);
        if (__all((int)ok)) break;
        __builtin_amdgcn_s_sleep(1);
      }
    }
    float xg[4];
    xg[0] = b2f((unsigned short)g0); xg[1] = b2f((unsigned short)(g0 >> 16));
    xg[2] = b2f((unsigned short)g1); xg[3] = b2f((unsigned short)(g1 >> 16));

    // ---- LN-A stats: intra-wg reduction over 2048 ----
    float S = xg[0] + xg[1] + xg[2] + xg[3];
    float Q = xg[0]*xg[0] + xg[1]*xg[1] + xg[2]*xg[2] + xg[3]*xg[3];
    #pragma unroll
    for (int o = 1; o < 64; o <<= 1){ S += __shfl_xor(S, o); Q += __shfl_xor(Q, o); }
    if (lane == 0){ red[w][0] = S; red[w][1] = Q; }
    __syncthreads();                                   // B1
    S = 0.f; Q = 0.f;
    #pragma unroll
    for (int w2 = 0; w2 < 8; ++w2){ S += red[w2][0]; Q += red[w2][1]; }
    const float muA = S * (1.f / 2048.f);
    const float invA = rsqrtf((Q - S * muA) + 1e-5f);

    // ---- gates + activations (4 gates of one type per thread) ----
    {
      const int gb4 = 4 * tid;
      f32x4 p2v = *(const f32x4*)&p2L[gb4];
      f32x4 psv = *(const f32x4*)&psbL[gb4];
      f32x4 av;
      #pragma unroll
      for (int j = 0; j < 4; ++j){
        const float gi_v = b2f((unsigned short)(giw >> (16 * j)));
        const float gv = gi_v + p2v[j] * ((xg[j] - muA) * invA) + psv[j];
        if ((tid >> 7) == 2) av[j] = tanhf(gv);
        else                 av[j] = 1.f / (1.f + __expf(-gv));
      }
      *(f32x4*)&actL[gb4] = av;
    }
    __syncthreads();                                   // B2

    // ---- c-candidate + LN-C (thread tid <-> col tid) ----
    const float i_g = actL[tid];
    const float f_g = actL[512 + tid];
    const float g_g = actL[1024 + tid];
    const float o_g = actL[1536 + tid];
    const float cc = f_g * c_val + i_g * g_g;
    float Sc = cc, Qc = cc * cc;
    #pragma unroll
    for (int o = 1; o < 64; o <<= 1){ Sc += __shfl_xor(Sc, o); Qc += __shfl_xor(Qc, o); }
    if (lane == 0){ red[w][0] = Sc; red[w][1] = Qc; }
    __syncthreads();                                   // B3
    Sc = 0.f; Qc = 0.f;
    #pragma unroll
    for (int w2 = 0; w2 < 8; ++w2){ Sc += red[w2][0]; Qc += red[w2][1]; }
    const float muC = Sc * (1.f / 512.f);
    const float invC = rsqrtf((Qc - Sc * muC) + 1e-5f);
    const float cn = b3j * ((cc - muC) * invC) + s3j;
    c_val = cn;
    const float h = o_g * tanhf(cn);

    out[((size_t)s_own * 512 + t) * 512 + tid] = h;
    if (t == 511){
      out[16777216u + (size_t)s_own * 512 + tid] = h;
      out[16777216u + 32768u + (size_t)s_own * 512 + tid] = cn;
    }

    // ---- hop H produce: post h(t+1) as tagged u64 pairs ----
    {
      const unsigned myb = f2b(h);
      const unsigned nb = (unsigned)__shfl_xor((int)myb, 1);
      const unsigned lo = (lane & 1) ? nb : myb;
      const unsigned hi = (lane & 1) ? myb : nb;
      const unsigned pair = lo | (hi << 16);
      if ((lane & 1) == 0){
        unsigned long long v = ((unsigned long long)(unsigned)(t + 1) << 32) |
                               (unsigned long long)pair;
        __hip_atomic_store(hbuf + (size_t)s_own * 256 + (tid >> 1), v,
                           __ATOMIC_RELAXED, __HIP_MEMORY_SCOPE_AGENT);
      }
    }
  }
}

extern "C" void kernel_launch(void* const* d_in, const int* in_sizes, int n_in,
                              void* d_out, int out_size, void* d_ws, size_t ws_size,
                              hipStream_t stream){
  (void)in_sizes; (void)n_in; (void)out_size; (void)ws_size;
  const float* x    = (const float*)d_in[0];
  const float* hx   = (const float*)d_in[1];
  const float* cx   = (const float*)d_in[2];
  const float* Wi   = (const float*)d_in[3];
  const float* Wh   = (const float*)d_in[4];
  const float* bias = (const float*)d_in[5];
  const float* b1   = (const float*)d_in[6];
  const float* b2   = (const float*)d_in[7];
  const float* b3   = (const float*)d_in[8];
  const float* s1   = (const float*)d_in[9];
  const float* s2   = (const float*)d_in[10];
  const float* s3   = (const float*)d_in[11];
  float* out = (float*)d_out;
  char* ws = (char*)d_ws;

  unsigned short*     xb   = (unsigned short*)(ws);                 //  33,554,432
  unsigned short*     wib  = (unsigned short*)(ws + 33554432);      //   2,097,152
  unsigned short*     whb  = (unsigned short*)(ws + 35651584);      //   2,097,152
  unsigned short*     gp   = (unsigned short*)(ws + 37748736);      // 134,217,728
  unsigned long long* hbuf = (unsigned long long*)(ws + 171966464); //     131,072
  unsigned long long* gbuf = (unsigned long long*)(ws + 172097536); //     524,288

  conv_bf16<<<16384, 256, 0, stream>>>(x,  xb,  4194304);
  conv_bf16<<<1024,  256, 0, stream>>>(Wi, wib, 262144);
  conv_bf16<<<1024,  256, 0, stream>>>(Wh, whb, 262144);
  init_h<<<64, 256, 0, stream>>>(hx, hbuf);
  gemm_gi<<<dim3(256, 16, 1), 256, 0, stream>>>(xb, wib, gp);
  ln_rows<<<32768, 256, 0, stream>>>(gp, b1, s1);
  lstm_rec<<<64, 512, 0, stream>>>(gp, whb, bias, b2, s2, b3, s3, cx,
                                   hbuf, gbuf, out);
}